// Round 1
// baseline (22699.268 us; speedup 1.0000x reference)
//
#include <hip/hip_runtime.h>

// LSTM encoder-decoder: B=512, F=1024, HIST=20, FUT=30, L=3, fp32.
// Round 0: correctness-first fp32 baseline.
//   per cell: gates[B,4F] = x@Wih^T + h@Whh^T + bih + bhh  (one fused GEMM kernel)
//             then elementwise LSTM cell update.
// 150 cells sequential on stream; decoder feeds h[2] (or c[2] at t=0) back as x.

#define BDIM 512
#define FDIM 1024
#define HISTLEN 20
#define LAYERS 3
#define NG 4096       // 4*F
#define KD 1024       // K = F

__device__ __forceinline__ float sigf(float x) { return 1.f / (1.f + __expf(-x)); }
__device__ __forceinline__ float tanh_fast(float x) {
    // stable: tanh(x) = sign(x) * (1 - e^{-2|x|}) / (1 + e^{-2|x|})
    float e = __expf(-2.f * fabsf(x));
    float r = (1.f - e) / (1.f + e);
    return copysignf(r, x);
}

// Gather x_t[b,f] = seq[b, f, t]  (seq is [B, F, HIST], t strided)
__global__ void pack_x(const float* __restrict__ seq, float* __restrict__ xp, int t) {
    int idx = blockIdx.x * blockDim.x + threadIdx.x;   // < B*F
    xp[idx] = seq[(size_t)idx * HISTLEN + t];
}

// Tiled fp32 GEMM: gates[M=512, N=4096] = A_x[512,1024]@Wi^T + A_h[512,1024]@Wh^T + bi + bh
// Wi, Wh are [N, K] row-major (K-contiguous -> coalesced float4 loads).
// BM=64 BN=128 BK=16, 512 threads, thread tile 4x4. grid = (32, 8) = 256 WGs.
constexpr int BM = 64, BN = 128, BK = 16;

__global__ __launch_bounds__(512) void gemm_gates(
    const float* __restrict__ Ax, const float* __restrict__ Ah,
    const float* __restrict__ Wi, const float* __restrict__ Wh,
    const float* __restrict__ bi, const float* __restrict__ bh,
    float* __restrict__ gates)
{
    __shared__ float As[BK][BM];       // k-major so compute reads are contiguous in m
    __shared__ float Bs[BK][BN];

    const int tid = threadIdx.x;
    const int m0 = blockIdx.y * BM;
    const int n0 = blockIdx.x * BN;
    const int tm = (tid & 15) * 4;     // 0..60
    const int tn = (tid >> 4) * 4;     // 0..124

    // staging indices: A tile 64x16 = 1024 floats -> float2/thread,
    //                  B tile 128x16 = 2048 floats -> float4/thread
    const int a_row = tid >> 3;        // 0..63
    const int a_col = (tid & 7) * 2;   // 0,2,..,14
    const int b_row = tid >> 2;        // 0..127
    const int b_col = (tid & 3) * 4;   // 0,4,8,12

    float acc[4][4] = {};

    for (int s = 0; s < 2; ++s) {
        const float* A  = s ? Ah : Ax;
        const float* Bm = s ? Wh : Wi;
        for (int k0 = 0; k0 < KD; k0 += BK) {
            float2 av = *(const float2*)(A  + (m0 + a_row) * KD + k0 + a_col);
            float4 bv = *(const float4*)(Bm + (n0 + b_row) * KD + k0 + b_col);
            As[a_col    ][a_row] = av.x;
            As[a_col + 1][a_row] = av.y;
            Bs[b_col    ][b_row] = bv.x;
            Bs[b_col + 1][b_row] = bv.y;
            Bs[b_col + 2][b_row] = bv.z;
            Bs[b_col + 3][b_row] = bv.w;
            __syncthreads();
            #pragma unroll
            for (int kk = 0; kk < BK; ++kk) {
                float4 a4 = *(const float4*)&As[kk][tm];
                float4 b4 = *(const float4*)&Bs[kk][tn];
                float a[4] = {a4.x, a4.y, a4.z, a4.w};
                float b[4] = {b4.x, b4.y, b4.z, b4.w};
                #pragma unroll
                for (int i = 0; i < 4; ++i)
                    #pragma unroll
                    for (int j = 0; j < 4; ++j)
                        acc[i][j] += a[i] * b[j];
            }
            __syncthreads();
        }
    }

    float4 bb;
    bb.x = bi[n0 + tn + 0] + bh[n0 + tn + 0];
    bb.y = bi[n0 + tn + 1] + bh[n0 + tn + 1];
    bb.z = bi[n0 + tn + 2] + bh[n0 + tn + 2];
    bb.w = bi[n0 + tn + 3] + bh[n0 + tn + 3];
    #pragma unroll
    for (int i = 0; i < 4; ++i) {
        float4 v;
        v.x = acc[i][0] + bb.x;
        v.y = acc[i][1] + bb.y;
        v.z = acc[i][2] + bb.z;
        v.w = acc[i][3] + bb.w;
        *(float4*)(gates + (size_t)(m0 + tm + i) * NG + n0 + tn) = v;
    }
}

// Elementwise LSTM cell update. gates layout [B, 4F] with gate order i,f,g,o.
// Optionally writes y (decoder top layer) to out[b,f,t] with stride fut.
__global__ void cell_update(const float* __restrict__ gates,
                            float* __restrict__ h, float* __restrict__ c,
                            float* __restrict__ y, int t, int fut)
{
    int idx = blockIdx.x * blockDim.x + threadIdx.x;   // < B*F
    int b = idx >> 10, f = idx & 1023;
    const float* gr = gates + (size_t)b * NG;
    float ig = gr[f];
    float fg = gr[FDIM + f];
    float gg = gr[2 * FDIM + f];
    float og = gr[3 * FDIM + f];
    float cold = c[idx];
    float cn = sigf(fg) * cold + sigf(ig) * tanh_fast(gg);
    float hn = sigf(og) * tanh_fast(cn);
    c[idx] = cn;
    h[idx] = hn;
    if (y) y[(size_t)idx * fut + t] = hn;
}

extern "C" void kernel_launch(void* const* d_in, const int* in_sizes, int n_in,
                              void* d_out, int out_size, void* d_ws, size_t ws_size,
                              hipStream_t stream)
{
    const float* seq = (const float*)d_in[0];
    const float* Wih = (const float*)d_in[1];
    const float* Whh = (const float*)d_in[2];
    const float* bih = (const float*)d_in[3];
    const float* bhh = (const float*)d_in[4];
    float* out = (float*)d_out;

    const int fut = out_size / (BDIM * FDIM);          // = 30; derived, no device read
    const size_t BF = (size_t)BDIM * FDIM;

    // workspace layout (floats): h[3][B][F] | c[3][B][F] | gates[B][4F] | xpack[B][F]
    float* h     = (float*)d_ws;
    float* c     = h + LAYERS * BF;
    float* gates = c + LAYERS * BF;
    float* xpack = gates + (size_t)BDIM * NG;

    hipMemsetAsync(h, 0, 2 * LAYERS * BF * sizeof(float), stream);   // zero h and c

    dim3 ggrid(NG / BN, BDIM / BM);                    // (32, 8) = 256 WGs
    const size_t Wsz = (size_t)NG * KD;                // per-layer weight elements

    // --- history (teacher-forced from seq_input) ---
    for (int t = 0; t < HISTLEN; ++t) {
        pack_x<<<BF / 256, 256, 0, stream>>>(seq, xpack, t);
        for (int l = 0; l < LAYERS; ++l) {
            const float* x = (l == 0) ? xpack : h + (size_t)(l - 1) * BF;
            gemm_gates<<<ggrid, 512, 0, stream>>>(x, h + (size_t)l * BF,
                Wih + (size_t)l * Wsz, Whh + (size_t)l * Wsz,
                bih + l * NG, bhh + l * NG, gates);
            cell_update<<<BF / 256, 256, 0, stream>>>(gates,
                h + (size_t)l * BF, c + (size_t)l * BF, nullptr, 0, fut);
        }
    }

    // --- decoder (free-running; first input is top-layer CELL state) ---
    for (int t = 0; t < fut; ++t) {
        for (int l = 0; l < LAYERS; ++l) {
            const float* x = (l == 0)
                ? ((t == 0) ? c + 2 * BF : h + 2 * BF)
                : h + (size_t)(l - 1) * BF;
            gemm_gates<<<ggrid, 512, 0, stream>>>(x, h + (size_t)l * BF,
                Wih + (size_t)l * Wsz, Whh + (size_t)l * Wsz,
                bih + l * NG, bhh + l * NG, gates);
            cell_update<<<BF / 256, 256, 0, stream>>>(gates,
                h + (size_t)l * BF, c + (size_t)l * BF,
                (l == LAYERS - 1) ? out : nullptr, t, fut);
        }
    }
}

// Round 2
// 8358.702 us; speedup vs baseline: 2.7156x; 2.7156x over previous
//
#include <hip/hip_runtime.h>

// LSTM encoder-decoder B=512 F=1024 HIST=20 FUT=30 L=3 (fp32 in/out).
// Round 2: split-bf16 MFMA GEMM (3-term hi/lo decomposition).
//   gates = x@Wih^T + h@Whh^T (+biases in cell kernel)
//   Each fp32 operand w = hi + lo (truncated bf16 each); products computed as
//   Ahi*Whi + Alo*Whi + Ahi*Wlo via v_mfma_f32_16x16x32_bf16 (lo*lo dropped,
//   rel err ~2^-16). Weights split on the fly in the GEMM staging phase
//   (same cache bytes as fp32); activations pre-split by the cell kernel.
// One GEMM launch per cell with gridDim.z=2: z=0 -> gx = x-part, z=1 -> gh = h-part.

#define BDIM 512
#define FDIM 1024
#define HISTLEN 20
#define LAYERS 3
#define NG 4096
#define KD 1024

typedef __attribute__((ext_vector_type(8))) short short8;   // 8 bf16 = 4 VGPRs
typedef __attribute__((ext_vector_type(4))) float f32x4;    // MFMA accumulator

__device__ __forceinline__ float sigf(float x) { return 1.f / (1.f + __expf(-x)); }
__device__ __forceinline__ float tanh_fast(float x) {
    float e = __expf(-2.f * fabsf(x));
    float r = (1.f - e) / (1.f + e);
    return copysignf(r, x);
}
__device__ __forceinline__ ushort bfhi(float w) { return (ushort)(__float_as_uint(w) >> 16); }
__device__ __forceinline__ float hif(float w) { return __uint_as_float(__float_as_uint(w) & 0xFFFF0000u); }
__device__ __forceinline__ ushort bflo(float w) { return bfhi(w - hif(w)); }

// ---------------- GEMM: out[z][512,4096] = A[z] @ W[z]^T ----------------
// A given as pre-split hi/lo bf16 [512,1024]; W fp32 [4096,1024] row-major
// (K-contiguous). Tiles: 128x128, BK=32, 256 threads = 4 waves of 64x64.
constexpr int LDT = 40;   // padded LDS row stride in bf16 elems (80 B -> 2-way max)

__global__ __launch_bounds__(256) void gemm_split(
    const ushort* __restrict__ A0hi, const ushort* __restrict__ A0lo,
    const float*  __restrict__ W0,   float* __restrict__ out0,
    const ushort* __restrict__ A1hi, const ushort* __restrict__ A1lo,
    const float*  __restrict__ W1,   float* __restrict__ out1)
{
    __shared__ __attribute__((aligned(16))) ushort WhiL[128 * LDT];
    __shared__ __attribute__((aligned(16))) ushort WloL[128 * LDT];
    __shared__ __attribute__((aligned(16))) ushort AhiL[128 * LDT];
    __shared__ __attribute__((aligned(16))) ushort AloL[128 * LDT];

    const int z = blockIdx.z;
    const ushort* Ahi = z ? A1hi : A0hi;
    const ushort* Alo = z ? A1lo : A0lo;
    const float*  W   = z ? W1 : W0;
    float*        out = z ? out1 : out0;

    const int tid = threadIdx.x;
    const int m0 = blockIdx.y * 128;
    const int n0 = blockIdx.x * 128;

    // staging: thread -> (row 0..127, 16-elem half)
    const int srow  = tid >> 1;
    const int shalf = tid & 1;
    const int s_lds = srow * LDT + shalf * 16;          // bf16 index, 16B aligned

    // wave/frag decomposition
    const int lane = tid & 63;
    const int wid  = tid >> 6;
    const int wm = (wid & 1) * 64;
    const int wn = (wid >> 1) * 64;
    const int frow = lane & 15;
    const int oct  = lane >> 4;

    int a_off[4], w_off[4];
    #pragma unroll
    for (int i = 0; i < 4; ++i) {
        a_off[i] = (wm + i * 16 + frow) * LDT + oct * 8;
        w_off[i] = (wn + i * 16 + frow) * LDT + oct * 8;
    }

    f32x4 acc[4][4] = {};

    const float*  wg_base = W   + (size_t)(n0 + srow) * KD + shalf * 16;
    const ushort* ah_base = Ahi + (size_t)(m0 + srow) * KD + shalf * 16;
    const ushort* al_base = Alo + (size_t)(m0 + srow) * KD + shalf * 16;

    for (int k0 = 0; k0 < KD; k0 += 32) {
        // global loads first (overlap with previous compute)
        float4 w4[4];
        #pragma unroll
        for (int q = 0; q < 4; ++q) w4[q] = *(const float4*)(wg_base + k0 + q * 4);
        short8 ah0 = *(const short8*)(ah_base + k0);
        short8 ah1 = *(const short8*)(ah_base + k0 + 8);
        short8 al0 = *(const short8*)(al_base + k0);
        short8 al1 = *(const short8*)(al_base + k0 + 8);

        // split W into hi/lo bf16
        ushort whi[16], wlo[16];
        #pragma unroll
        for (int e = 0; e < 16; ++e) {
            float w = ((const float*)w4)[e];
            unsigned u = __float_as_uint(w);
            whi[e] = (ushort)(u >> 16);
            float r = w - __uint_as_float(u & 0xFFFF0000u);
            wlo[e] = (ushort)(__float_as_uint(r) >> 16);
        }

        __syncthreads();   // previous iteration's LDS reads done
        *(short8*)&WhiL[s_lds]     = *(short8*)&whi[0];
        *(short8*)&WhiL[s_lds + 8] = *(short8*)&whi[8];
        *(short8*)&WloL[s_lds]     = *(short8*)&wlo[0];
        *(short8*)&WloL[s_lds + 8] = *(short8*)&wlo[8];
        *(short8*)&AhiL[s_lds]     = ah0;
        *(short8*)&AhiL[s_lds + 8] = ah1;
        *(short8*)&AloL[s_lds]     = al0;
        *(short8*)&AloL[s_lds + 8] = al1;
        __syncthreads();

        short8 fa_hi[4], fa_lo[4];
        #pragma unroll
        for (int i = 0; i < 4; ++i) {
            fa_hi[i] = *(const short8*)&AhiL[a_off[i]];
            fa_lo[i] = *(const short8*)&AloL[a_off[i]];
        }
        #pragma unroll
        for (int j = 0; j < 4; ++j) {
            short8 fb_hi = *(const short8*)&WhiL[w_off[j]];
            short8 fb_lo = *(const short8*)&WloL[w_off[j]];
            #pragma unroll
            for (int i = 0; i < 4; ++i) {
                acc[i][j] = __builtin_amdgcn_mfma_f32_16x16x32_bf16(fa_hi[i], fb_hi, acc[i][j], 0, 0, 0);
                acc[i][j] = __builtin_amdgcn_mfma_f32_16x16x32_bf16(fa_lo[i], fb_hi, acc[i][j], 0, 0, 0);
                acc[i][j] = __builtin_amdgcn_mfma_f32_16x16x32_bf16(fa_hi[i], fb_lo, acc[i][j], 0, 0, 0);
            }
        }
    }

    // epilogue: C/D layout row=(lane>>4)*4+reg, col=lane&15 (verified m89/m91)
    #pragma unroll
    for (int i = 0; i < 4; ++i) {
        #pragma unroll
        for (int j = 0; j < 4; ++j) {
            int col = n0 + wn + j * 16 + frow;
            #pragma unroll
            for (int r = 0; r < 4; ++r) {
                int row = m0 + wm + i * 16 + oct * 4 + r;
                out[(size_t)row * NG + col] = acc[i][j][r];
            }
        }
    }
}

// ---------------- elementwise cell update (fused gate-sum + split-h) ----------------
__global__ void cell_fuse(const float* __restrict__ gx, const float* __restrict__ gh,
                          const float* __restrict__ bi, const float* __restrict__ bh,
                          float* __restrict__ c,
                          ushort* __restrict__ Hhi, ushort* __restrict__ Hlo,
                          float* __restrict__ y, int t, int fut)
{
    int idx = blockIdx.x * blockDim.x + threadIdx.x;   // < B*F
    int b = idx >> 10, f = idx & 1023;
    const float* gxr = gx + (size_t)b * NG;
    const float* ghr = gh + (size_t)b * NG;
    float ig = gxr[f]            + ghr[f]            + bi[f]            + bh[f];
    float fg = gxr[FDIM + f]     + ghr[FDIM + f]     + bi[FDIM + f]     + bh[FDIM + f];
    float gg = gxr[2 * FDIM + f] + ghr[2 * FDIM + f] + bi[2 * FDIM + f] + bh[2 * FDIM + f];
    float og = gxr[3 * FDIM + f] + ghr[3 * FDIM + f] + bi[3 * FDIM + f] + bh[3 * FDIM + f];
    float cn = sigf(fg) * c[idx] + sigf(ig) * tanh_fast(gg);
    float hn = sigf(og) * tanh_fast(cn);
    c[idx] = cn;
    Hhi[idx] = bfhi(hn);
    Hlo[idx] = bflo(hn);
    if (y) y[(size_t)idx * fut + t] = hn;
}

// x_t from seq [B,F,HIST] -> split bf16
__global__ void pack_split(const float* __restrict__ seq,
                           ushort* __restrict__ Xhi, ushort* __restrict__ Xlo, int t)
{
    int idx = blockIdx.x * blockDim.x + threadIdx.x;
    float v = seq[(size_t)idx * HISTLEN + t];
    Xhi[idx] = bfhi(v);
    Xlo[idx] = bflo(v);
}

// fp32 vector -> split bf16 (decoder t=0 input = c[2])
__global__ void split_vec(const float* __restrict__ src,
                          ushort* __restrict__ hi, ushort* __restrict__ lo)
{
    int idx = blockIdx.x * blockDim.x + threadIdx.x;
    float v = src[idx];
    hi[idx] = bfhi(v);
    lo[idx] = bflo(v);
}

extern "C" void kernel_launch(void* const* d_in, const int* in_sizes, int n_in,
                              void* d_out, int out_size, void* d_ws, size_t ws_size,
                              hipStream_t stream)
{
    const float* seq = (const float*)d_in[0];
    const float* Wih = (const float*)d_in[1];
    const float* Whh = (const float*)d_in[2];
    const float* bih = (const float*)d_in[3];
    const float* bhh = (const float*)d_in[4];
    float* out = (float*)d_out;

    const int fut = out_size / (BDIM * FDIM);           // 30
    const size_t BF = (size_t)BDIM * FDIM;
    const size_t Wsz = (size_t)NG * KD;

    // ws layout: c[3BF]f32 | Hhi[3BF]u16 | Hlo[3BF]u16 | Xhi[BF]u16 | Xlo[BF]u16 | gx | gh
    float*  c   = (float*)d_ws;
    ushort* Hhi = (ushort*)(c + LAYERS * BF);
    ushort* Hlo = Hhi + LAYERS * BF;
    ushort* Xhi = Hlo + LAYERS * BF;
    ushort* Xlo = Xhi + BF;
    float*  gx  = (float*)(Xlo + BF);
    float*  gh  = gx + (size_t)BDIM * NG;

    // zero c, Hhi, Hlo (contiguous: 3BF*4 + 3BF*2 + 3BF*2 = 3BF*8 bytes)
    hipMemsetAsync(d_ws, 0, LAYERS * BF * 8, stream);

    dim3 ggrid(NG / 128, BDIM / 128, 2);                // (32, 4, 2) = 256 WGs
    const int cgrid = (int)(BF / 256);

    for (int t = 0; t < HISTLEN + fut; ++t) {
        const bool dec = (t >= HISTLEN);
        if (!dec) {
            pack_split<<<cgrid, 256, 0, stream>>>(seq, Xhi, Xlo, t);
        } else if (t == HISTLEN) {
            split_vec<<<cgrid, 256, 0, stream>>>(c + 2 * BF, Xhi, Xlo);
        }
        for (int l = 0; l < LAYERS; ++l) {
            const ushort* axh;
            const ushort* axl;
            if (l > 0)        { axh = Hhi + (size_t)(l - 1) * BF; axl = Hlo + (size_t)(l - 1) * BF; }
            else if (!dec || t == HISTLEN) { axh = Xhi; axl = Xlo; }
            else              { axh = Hhi + 2 * BF; axl = Hlo + 2 * BF; }

            gemm_split<<<ggrid, 256, 0, stream>>>(
                axh, axl, Wih + (size_t)l * Wsz, gx,
                Hhi + (size_t)l * BF, Hlo + (size_t)l * BF, Whh + (size_t)l * Wsz, gh);

            cell_fuse<<<cgrid, 256, 0, stream>>>(
                gx, gh, bih + l * NG, bhh + l * NG,
                c + (size_t)l * BF, Hhi + (size_t)l * BF, Hlo + (size_t)l * BF,
                (dec && l == LAYERS - 1) ? out : nullptr, dec ? t - HISTLEN : 0, fut);
        }
    }
}

// Round 3
// 6496.932 us; speedup vs baseline: 3.4938x; 1.2866x over previous
//
#include <hip/hip_runtime.h>

// LSTM encoder-decoder B=512 F=1024 HIST=20 FUT=30 L=3 (fp32 in/out).
// Round 3: round-2 split-bf16 MFMA GEMM + split-K=2 for occupancy.
//   Round-2 diagnosis: grid was 256 blocks = 1 block/CU = 1 wave/SIMD -> all
//   LDS/global latency + barrier drains fully exposed (50us/GEMM vs ~10us LDS
//   roofline). Fix: gridDim.z=4 (z = {x,h} x {k-half}) -> 512 blocks =
//   2 blocks/CU = 2 waves/SIMD. fp32 partials summed in cell_fuse.

#define BDIM 512
#define FDIM 1024
#define HISTLEN 20
#define LAYERS 3
#define NG 4096
#define KD 1024

typedef __attribute__((ext_vector_type(8))) short short8;   // 8 bf16 = 4 VGPRs
typedef __attribute__((ext_vector_type(4))) float f32x4;    // MFMA accumulator

__device__ __forceinline__ float sigf(float x) { return 1.f / (1.f + __expf(-x)); }
__device__ __forceinline__ float tanh_fast(float x) {
    float e = __expf(-2.f * fabsf(x));
    float r = (1.f - e) / (1.f + e);
    return copysignf(r, x);
}
__device__ __forceinline__ ushort bfhi(float w) { return (ushort)(__float_as_uint(w) >> 16); }
__device__ __forceinline__ float hif(float w) { return __uint_as_float(__float_as_uint(w) & 0xFFFF0000u); }
__device__ __forceinline__ ushort bflo(float w) { return bfhi(w - hif(w)); }

// ---------------- GEMM: gp[z][512,4096] partial = A(s) @ W(s)^T over k-half ----
// z = kh*2 + s;  s: 0 -> (A0, W0) [x-part], 1 -> (A1, W1) [h-part]
// A pre-split hi/lo bf16 [512,1024]; W fp32 [4096,1024] row-major, split on the fly.
// Tiles: 128x128, BK=32, 256 threads = 4 waves of 64x64. 512 blocks = 2/CU.
constexpr int LDT = 40;   // padded LDS row stride in bf16 elems (2-way max conflicts)

__global__ __launch_bounds__(256, 2) void gemm_split(
    const ushort* __restrict__ A0hi, const ushort* __restrict__ A0lo,
    const float*  __restrict__ W0,
    const ushort* __restrict__ A1hi, const ushort* __restrict__ A1lo,
    const float*  __restrict__ W1,
    float* __restrict__ gp)   // 4 partials of [512,4096], z-th at gp + z*M*NG
{
    __shared__ __attribute__((aligned(16))) ushort WhiL[128 * LDT];
    __shared__ __attribute__((aligned(16))) ushort WloL[128 * LDT];
    __shared__ __attribute__((aligned(16))) ushort AhiL[128 * LDT];
    __shared__ __attribute__((aligned(16))) ushort AloL[128 * LDT];

    const int z  = blockIdx.z;
    const int s  = z & 1;
    const int kh = z >> 1;
    const ushort* Ahi = s ? A1hi : A0hi;
    const ushort* Alo = s ? A1lo : A0lo;
    const float*  W   = s ? W1 : W0;
    float*        out = gp + (size_t)z * BDIM * NG;

    const int tid = threadIdx.x;
    const int m0 = blockIdx.y * 128;
    const int n0 = blockIdx.x * 128;

    const int srow  = tid >> 1;
    const int shalf = tid & 1;
    const int s_lds = srow * LDT + shalf * 16;

    const int lane = tid & 63;
    const int wid  = tid >> 6;
    const int wm = (wid & 1) * 64;
    const int wn = (wid >> 1) * 64;
    const int frow = lane & 15;
    const int oct  = lane >> 4;

    int a_off[4], w_off[4];
    #pragma unroll
    for (int i = 0; i < 4; ++i) {
        a_off[i] = (wm + i * 16 + frow) * LDT + oct * 8;
        w_off[i] = (wn + i * 16 + frow) * LDT + oct * 8;
    }

    f32x4 acc[4][4] = {};

    const float*  wg_base = W   + (size_t)(n0 + srow) * KD + shalf * 16;
    const ushort* ah_base = Ahi + (size_t)(m0 + srow) * KD + shalf * 16;
    const ushort* al_base = Alo + (size_t)(m0 + srow) * KD + shalf * 16;

    const int kbeg = kh * (KD / 2);
    const int kend = kbeg + KD / 2;

    for (int k0 = kbeg; k0 < kend; k0 += 32) {
        float4 w4[4];
        #pragma unroll
        for (int q = 0; q < 4; ++q) w4[q] = *(const float4*)(wg_base + k0 + q * 4);
        short8 ah0 = *(const short8*)(ah_base + k0);
        short8 ah1 = *(const short8*)(ah_base + k0 + 8);
        short8 al0 = *(const short8*)(al_base + k0);
        short8 al1 = *(const short8*)(al_base + k0 + 8);

        ushort whi[16], wlo[16];
        #pragma unroll
        for (int e = 0; e < 16; ++e) {
            float w = ((const float*)w4)[e];
            unsigned u = __float_as_uint(w);
            whi[e] = (ushort)(u >> 16);
            float r = w - __uint_as_float(u & 0xFFFF0000u);
            wlo[e] = (ushort)(__float_as_uint(r) >> 16);
        }

        __syncthreads();
        *(short8*)&WhiL[s_lds]     = *(short8*)&whi[0];
        *(short8*)&WhiL[s_lds + 8] = *(short8*)&whi[8];
        *(short8*)&WloL[s_lds]     = *(short8*)&wlo[0];
        *(short8*)&WloL[s_lds + 8] = *(short8*)&wlo[8];
        *(short8*)&AhiL[s_lds]     = ah0;
        *(short8*)&AhiL[s_lds + 8] = ah1;
        *(short8*)&AloL[s_lds]     = al0;
        *(short8*)&AloL[s_lds + 8] = al1;
        __syncthreads();

        short8 fa_hi[4], fa_lo[4];
        #pragma unroll
        for (int i = 0; i < 4; ++i) {
            fa_hi[i] = *(const short8*)&AhiL[a_off[i]];
            fa_lo[i] = *(const short8*)&AloL[a_off[i]];
        }
        #pragma unroll
        for (int j = 0; j < 4; ++j) {
            short8 fb_hi = *(const short8*)&WhiL[w_off[j]];
            short8 fb_lo = *(const short8*)&WloL[w_off[j]];
            #pragma unroll
            for (int i = 0; i < 4; ++i) {
                acc[i][j] = __builtin_amdgcn_mfma_f32_16x16x32_bf16(fa_hi[i], fb_hi, acc[i][j], 0, 0, 0);
                acc[i][j] = __builtin_amdgcn_mfma_f32_16x16x32_bf16(fa_lo[i], fb_hi, acc[i][j], 0, 0, 0);
                acc[i][j] = __builtin_amdgcn_mfma_f32_16x16x32_bf16(fa_hi[i], fb_lo, acc[i][j], 0, 0, 0);
            }
        }
    }

    // C/D layout: row=(lane>>4)*4+reg, col=lane&15 (verified m89/m91)
    #pragma unroll
    for (int i = 0; i < 4; ++i) {
        #pragma unroll
        for (int j = 0; j < 4; ++j) {
            int col = n0 + wn + j * 16 + frow;
            #pragma unroll
            for (int r = 0; r < 4; ++r) {
                int row = m0 + wm + i * 16 + oct * 4 + r;
                out[(size_t)row * NG + col] = acc[i][j][r];
            }
        }
    }
}

// ---------------- elementwise cell update (sum 4 partials + biases) ------------
__global__ void cell_fuse(const float* __restrict__ gp,
                          const float* __restrict__ bi, const float* __restrict__ bh,
                          float* __restrict__ c,
                          ushort* __restrict__ Hhi, ushort* __restrict__ Hlo,
                          float* __restrict__ y, int t, int fut)
{
    const size_t MN = (size_t)BDIM * NG;
    int idx = blockIdx.x * blockDim.x + threadIdx.x;   // < B*F
    int b = idx >> 10, f = idx & 1023;
    const float* g0 = gp + (size_t)b * NG;
    const float* g1 = g0 + MN;
    const float* g2 = g1 + MN;
    const float* g3 = g2 + MN;
    float ig = g0[f] + g1[f] + g2[f] + g3[f] + bi[f] + bh[f];
    float fg = g0[FDIM + f] + g1[FDIM + f] + g2[FDIM + f] + g3[FDIM + f]
             + bi[FDIM + f] + bh[FDIM + f];
    float gg = g0[2 * FDIM + f] + g1[2 * FDIM + f] + g2[2 * FDIM + f] + g3[2 * FDIM + f]
             + bi[2 * FDIM + f] + bh[2 * FDIM + f];
    float og = g0[3 * FDIM + f] + g1[3 * FDIM + f] + g2[3 * FDIM + f] + g3[3 * FDIM + f]
             + bi[3 * FDIM + f] + bh[3 * FDIM + f];
    float cn = sigf(fg) * c[idx] + sigf(ig) * tanh_fast(gg);
    float hn = sigf(og) * tanh_fast(cn);
    c[idx] = cn;
    Hhi[idx] = bfhi(hn);
    Hlo[idx] = bflo(hn);
    if (y) y[(size_t)idx * fut + t] = hn;
}

// x_t from seq [B,F,HIST] -> split bf16
__global__ void pack_split(const float* __restrict__ seq,
                           ushort* __restrict__ Xhi, ushort* __restrict__ Xlo, int t)
{
    int idx = blockIdx.x * blockDim.x + threadIdx.x;
    float v = seq[(size_t)idx * HISTLEN + t];
    Xhi[idx] = bfhi(v);
    Xlo[idx] = bflo(v);
}

// fp32 vector -> split bf16 (decoder t=0 input = c[2])
__global__ void split_vec(const float* __restrict__ src,
                          ushort* __restrict__ hi, ushort* __restrict__ lo)
{
    int idx = blockIdx.x * blockDim.x + threadIdx.x;
    float v = src[idx];
    hi[idx] = bfhi(v);
    lo[idx] = bflo(v);
}

extern "C" void kernel_launch(void* const* d_in, const int* in_sizes, int n_in,
                              void* d_out, int out_size, void* d_ws, size_t ws_size,
                              hipStream_t stream)
{
    const float* seq = (const float*)d_in[0];
    const float* Wih = (const float*)d_in[1];
    const float* Whh = (const float*)d_in[2];
    const float* bih = (const float*)d_in[3];
    const float* bhh = (const float*)d_in[4];
    float* out = (float*)d_out;

    const int fut = out_size / (BDIM * FDIM);           // 30
    const size_t BF = (size_t)BDIM * FDIM;
    const size_t Wsz = (size_t)NG * KD;
    const size_t MN  = (size_t)BDIM * NG;

    // ws layout: c[3BF]f32 | Hhi[3BF]u16 | Hlo[3BF]u16 | Xhi[BF]u16 | Xlo[BF]u16 | gp[4*MN]f32
    float*  c   = (float*)d_ws;
    ushort* Hhi = (ushort*)(c + LAYERS * BF);
    ushort* Hlo = Hhi + LAYERS * BF;
    ushort* Xhi = Hlo + LAYERS * BF;
    ushort* Xlo = Xhi + BF;
    float*  gp  = (float*)(Xlo + BF);

    hipMemsetAsync(d_ws, 0, LAYERS * BF * 8, stream);   // zero c, Hhi, Hlo

    dim3 ggrid(NG / 128, BDIM / 128, 4);                // (32, 4, 4) = 512 WGs
    const int cgrid = (int)(BF / 256);

    for (int t = 0; t < HISTLEN + fut; ++t) {
        const bool dec = (t >= HISTLEN);
        if (!dec) {
            pack_split<<<cgrid, 256, 0, stream>>>(seq, Xhi, Xlo, t);
        } else if (t == HISTLEN) {
            split_vec<<<cgrid, 256, 0, stream>>>(c + 2 * BF, Xhi, Xlo);
        }
        for (int l = 0; l < LAYERS; ++l) {
            const ushort* axh;
            const ushort* axl;
            if (l > 0)        { axh = Hhi + (size_t)(l - 1) * BF; axl = Hlo + (size_t)(l - 1) * BF; }
            else if (!dec || t == HISTLEN) { axh = Xhi; axl = Xlo; }
            else              { axh = Hhi + 2 * BF; axl = Hlo + 2 * BF; }

            gemm_split<<<ggrid, 256, 0, stream>>>(
                axh, axl, Wih + (size_t)l * Wsz,
                Hhi + (size_t)l * BF, Hlo + (size_t)l * BF, Whh + (size_t)l * Wsz,
                gp);

            cell_fuse<<<cgrid, 256, 0, stream>>>(
                gp, bih + l * NG, bhh + l * NG,
                c + (size_t)l * BF, Hhi + (size_t)l * BF, Hlo + (size_t)l * BF,
                (dec && l == LAYERS - 1) ? out : nullptr, dec ? t - HISTLEN : 0, fut);
        }
    }
}